// Round 2
// baseline (886.102 us; speedup 1.0000x reference)
//
#include <hip/hip_runtime.h>
#include <hip/hip_bf16.h>

#define CURV 2.3026f
#define EPSF 1e-15f

typedef __attribute__((ext_vector_type(8))) short bfrag8;
typedef __attribute__((ext_vector_type(4))) float ffrag4;

__device__ __forceinline__ unsigned short f2bf(float f) {
  unsigned u = __builtin_bit_cast(unsigned, f);
  u += 0x7fffu + ((u >> 16) & 1u);
  return (unsigned short)(u >> 16);
}
__device__ __forceinline__ float bflo(unsigned u){ return __builtin_bit_cast(float, u << 16); }
__device__ __forceinline__ float bfhi(unsigned u){ return __builtin_bit_cast(float, u & 0xffff0000u); }

// ---- weight prep: per-column ||z||, cosh/sinh stats, bf16 transposed copy ----
__global__ void prep_weights(const float* __restrict__ z, const float* __restrict__ r,
                             unsigned short* __restrict__ zT, float* __restrict__ stats,
                             int K, int N) {
  int n = blockIdx.x;
  int t = threadIdx.x; // 128
  float ss = 0.f;
  for (int k = t; k < K; k += 128) {
    float v = z[(long)k * N + n];
    ss += v * v;
    zT[(long)n * K + k] = f2bf(v);
  }
  __shared__ float red[128];
  red[t] = ss;
  __syncthreads();
  for (int s = 64; s > 0; s >>= 1) { if (t < s) red[t] += red[t + s]; __syncthreads(); }
  if (t == 0) {
    float zn = fmaxf(sqrtf(red[0]), EPSF);
    float cs = sqrtf(CURV);
    float tc = 2.f * cs * r[n];
    stats[3*n+0] = 2.f * zn;        // 2*zn
    stats[3*n+1] = coshf(tc) / zn;  // cosh(tcr)/zn
    stats[3*n+2] = sinhf(tc);       // sinh(tcr)
  }
}

// ---- fused hlinear (+ hrelu) layer: C[64 x N] = A[64 x K] @ z[K x N], full epilogue ----
// Wave layout: 8 waves as 2 (M) x 4 (N); wave tile = 32 rows x N/4 cols; 16x16x32 bf16 MFMA.
// A-frag:  A[m = lane&15][k = (lane>>4)*8 + j]      (verified layout)
// B-frag:  B[k = (lane>>4)*8 + j][n = lane&15]      (LDS holds z^T so reads are contiguous)
// C/D:     col = lane&15, row = (lane>>4)*4 + reg   (verified layout)
template<int K, int N, bool FIRST>
__launch_bounds__(512)
__global__ void hlayer(const void* __restrict__ Ain,          // FIRST: float BxK, else bf16 BxK
                       const unsigned short* __restrict__ zT, // N x K bf16
                       const float* __restrict__ stats,       // N x 3
                       const float* __restrict__ lamIn,       // B (unused if FIRST)
                       unsigned short* __restrict__ Hout,     // B x N bf16
                       float* __restrict__ lamOut) {          // B
  constexpr int BK = 32, AP = 40, NT = N / 64;
  __shared__ unsigned short As[64 * AP];
  __shared__ unsigned short Bs[N * AP];
  __shared__ float rowstat[64];
  __shared__ float lamS[64];
  __shared__ float sums[64][2];
  __shared__ float gamS[64];

  const int t = threadIdx.x;
  const int wid = t >> 6, lane = t & 63;
  const int wm = wid >> 2, wn = wid & 3;
  const int lm = lane & 15, quad = lane >> 4;
  const int lk = quad * 8;
  const int nb = (N / 4) * wn;
  const long rowg0 = (long)blockIdx.x * 64;

  if (t < 64) {
    sums[t][0] = 0.f; sums[t][1] = 0.f;
    if (FIRST) rowstat[t] = 0.f;
    else       lamS[t] = lamIn[rowg0 + t];
  }
  __syncthreads();

  ffrag4 acc[2][NT];
#pragma unroll
  for (int a = 0; a < 2; a++)
#pragma unroll
    for (int b = 0; b < NT; b++) acc[a][b] = (ffrag4){0.f, 0.f, 0.f, 0.f};

  const float* Af = (const float*)Ain;
  const unsigned short* Ah = (const unsigned short*)Ain;

  for (int k0 = 0; k0 < K; k0 += BK) {
    // ---- stage A tile (64 x 32) ----
    if (FIRST) {
      int rr = t >> 3, q = t & 7;                         // 8 threads/row, float4 each
      float4 v = *reinterpret_cast<const float4*>(Af + (rowg0 + rr) * K + k0 + 4 * q);
      ushort4 b4; b4.x = f2bf(v.x); b4.y = f2bf(v.y); b4.z = f2bf(v.z); b4.w = f2bf(v.w);
      *reinterpret_cast<ushort4*>(&As[rr * AP + 4 * q]) = b4;
      atomicAdd(&rowstat[rr], v.x*v.x + v.y*v.y + v.z*v.z + v.w*v.w);
    } else {
      int rr = t >> 3, q = t & 7;                         // 8 threads/row, 4 bf16 each (FIXED)
      *reinterpret_cast<uint2*>(&As[rr * AP + 4 * q]) =
          *reinterpret_cast<const uint2*>(Ah + (rowg0 + rr) * K + k0 + 4 * q);
    }
    // ---- stage B tile (N x 32), from z^T so reads are row-contiguous ----
#pragma unroll
    for (int p = 0; p < N / 128; p++) {
      int n = p * 128 + (t >> 2), q = t & 3;
      *reinterpret_cast<uint4*>(&Bs[n * AP + 8 * q]) =
          *reinterpret_cast<const uint4*>(zT + (long)n * K + k0 + 8 * q);
    }
    __syncthreads();
    // ---- MFMA: one K-step of 32 ----
    bfrag8 af0 = *reinterpret_cast<const bfrag8*>(&As[(32 * wm + lm) * AP + lk]);
    bfrag8 af1 = *reinterpret_cast<const bfrag8*>(&As[(32 * wm + 16 + lm) * AP + lk]);
#pragma unroll
    for (int tn = 0; tn < NT; tn++) {
      bfrag8 bfr = *reinterpret_cast<const bfrag8*>(&Bs[(nb + 16 * tn + lm) * AP + lk]);
      acc[0][tn] = __builtin_amdgcn_mfma_f32_16x16x32_bf16(af0, bfr, acc[0][tn], 0, 0, 0);
      acc[1][tn] = __builtin_amdgcn_mfma_f32_16x16x32_bf16(af1, bfr, acc[1][tn], 0, 0, 0);
    }
    __syncthreads();
  }

  const float cs = sqrtf(CURV), inv_cs = 1.f / cs;

  if (FIRST) {
    if (t < 64) lamS[t] = 2.f / (1.f - CURV * rowstat[t]);
    __syncthreads();
  }

  // ---- epilogue: s -> w (in-place in acc) ----
#pragma unroll
  for (int tm = 0; tm < 2; tm++) {
#pragma unroll
    for (int tn = 0; tn < NT; tn++) {
      int cg = nb + 16 * tn + lm;
      float zn2 = stats[3 * cg + 0], chozn = stats[3 * cg + 1], sh = stats[3 * cg + 2];
#pragma unroll
      for (int rg = 0; rg < 4; rg++) {
        int row = 32 * wm + 16 * tm + 4 * quad + rg;
        float lam = lamS[row];
        float s = acc[tm][tn][rg];
        float arg = cs * lam * s * chozn - (lam - 1.f) * sh;
        float w = sinhf(zn2 * asinhf(arg)) * inv_cs;
        acc[tm][tn][rg] = w;
      }
    }
  }
  // ---- row reductions: sum w^2 and max(w,0)^2 over the full row ----
#pragma unroll
  for (int tm = 0; tm < 2; tm++) {
#pragma unroll
    for (int rg = 0; rg < 4; rg++) {
      float s2 = 0.f, sp2 = 0.f;
#pragma unroll
      for (int tn = 0; tn < NT; tn++) {
        float w = acc[tm][tn][rg];
        s2 += w * w;
        float wp = fmaxf(w, 0.f);
        sp2 += wp * wp;
      }
#pragma unroll
      for (int m = 1; m <= 8; m <<= 1) {
        s2 += __shfl_xor(s2, m, 16);
        sp2 += __shfl_xor(sp2, m, 16);
      }
      if (lm == 0) {
        int row = 32 * wm + 16 * tm + 4 * quad + rg;
        atomicAdd(&sums[row][0], s2);
        atomicAdd(&sums[row][1], sp2);
      }
    }
  }
  __syncthreads();
  // ---- per-row scalars: project into ball + fused hrelu scale ----
  if (t < 64) {
    float sw2 = sums[t][0], swp2 = sums[t][1];
    float den = 1.f + sqrtf(1.f + CURV * sw2);
    float nn = fmaxf(sqrtf(sw2) / den, EPSF);
    float al = atanhf(fminf(cs * nn, 1.f - 1e-7f)) / (cs * nn);
    float vn = fmaxf(al * sqrtf(swp2) / den, EPSF);
    float be = tanhf(cs * vn) / (cs * vn);
    float gam = be * al / den;
    gamS[t] = gam;
    float hn2 = gam * gam * swp2;
    lamOut[rowg0 + t] = 2.f / (1.f - CURV * hn2);
  }
  __syncthreads();
  // ---- write h = gamma * max(w,0) as bf16 ----
#pragma unroll
  for (int tm = 0; tm < 2; tm++) {
#pragma unroll
    for (int rg = 0; rg < 4; rg++) {
      int row = 32 * wm + 16 * tm + 4 * quad + rg;
      float gam = gamS[row];
#pragma unroll
      for (int tn = 0; tn < NT; tn++) {
        int cg = nb + 16 * tn + lm;
        Hout[(rowg0 + row) * N + cg] = f2bf(gam * fmaxf(acc[tm][tn][rg], 0.f));
      }
    }
  }
}

// ---- last layer: fo = 1, plain dot + hlinear epilogue ----
__global__ __launch_bounds__(256) void hlayer_last(const unsigned short* __restrict__ H, // B x 128 bf16
                            const float* __restrict__ z4,        // 128
                            const float* __restrict__ st4,       // 3
                            const float* __restrict__ lamIn,     // B
                            float* __restrict__ out) {           // B
  int t = threadIdx.x;
  long row = (long)blockIdx.x * 64 + (t >> 2);
  int p = t & 3;
  const uint4* hv = reinterpret_cast<const uint4*>(H + row * 128 + 32 * p);
  const float4* zv = reinterpret_cast<const float4*>(z4 + 32 * p);
  float s = 0.f;
#pragma unroll
  for (int i = 0; i < 4; i++) {
    uint4 hh = hv[i];
    float4 z0 = zv[2 * i], z1 = zv[2 * i + 1];
    s += bflo(hh.x) * z0.x + bfhi(hh.x) * z0.y + bflo(hh.y) * z0.z + bfhi(hh.y) * z0.w;
    s += bflo(hh.z) * z1.x + bfhi(hh.z) * z1.y + bflo(hh.w) * z1.z + bfhi(hh.w) * z1.w;
  }
  s += __shfl_down(s, 2, 4);
  s += __shfl_down(s, 1, 4);
  if (p == 0) {
    float cs = sqrtf(CURV);
    float lam = lamIn[row];
    float zn2 = st4[0], chozn = st4[1], sh = st4[2];
    float arg = cs * lam * s * chozn - (lam - 1.f) * sh;
    float w = sinhf(zn2 * asinhf(arg)) / cs;
    out[row] = w / (1.f + sqrtf(1.f + CURV * w * w));
  }
}

extern "C" void kernel_launch(void* const* d_in, const int* in_sizes, int n_in,
                              void* d_out, int out_size, void* d_ws, size_t ws_size,
                              hipStream_t stream) {
  const float* x  = (const float*)d_in[0];
  const float* z1 = (const float*)d_in[1];
  const float* b1 = (const float*)d_in[2];
  const float* z2 = (const float*)d_in[3];
  const float* b2 = (const float*)d_in[4];
  const float* z3 = (const float*)d_in[5];
  const float* b3 = (const float*)d_in[6];
  const float* z4 = (const float*)d_in[7];
  const float* b4 = (const float*)d_in[8];

  char* ws = (char*)d_ws;
  size_t off = 0;
  auto carve = [&](size_t bytes) { char* p = ws + off; off += (bytes + 255) & ~(size_t)255; return p; };
  unsigned short* zT1 = (unsigned short*)carve(512 * 768 * 2);
  unsigned short* zT2 = (unsigned short*)carve(256 * 512 * 2);
  unsigned short* zT3 = (unsigned short*)carve(128 * 256 * 2);
  unsigned short* zT4 = (unsigned short*)carve(1 * 128 * 2);
  float* st1 = (float*)carve(512 * 3 * 4);
  float* st2 = (float*)carve(256 * 3 * 4);
  float* st3 = (float*)carve(128 * 3 * 4);
  float* st4 = (float*)carve(3 * 4);
  float* lam1 = (float*)carve(65536 * 4);
  float* lam2 = (float*)carve(65536 * 4);
  float* lam3 = (float*)carve(65536 * 4);
  unsigned short* h1 = (unsigned short*)carve((size_t)65536 * 512 * 2);
  unsigned short* h2 = (unsigned short*)carve((size_t)65536 * 256 * 2);
  unsigned short* h3 = h1; // h1 dead after layer 2 reads it; alias to cap ws usage

  prep_weights<<<dim3(512), dim3(128), 0, stream>>>(z1, b1, zT1, st1, 768, 512);
  prep_weights<<<dim3(256), dim3(128), 0, stream>>>(z2, b2, zT2, st2, 512, 256);
  prep_weights<<<dim3(128), dim3(128), 0, stream>>>(z3, b3, zT3, st3, 256, 128);
  prep_weights<<<dim3(1),   dim3(128), 0, stream>>>(z4, b4, zT4, st4, 128, 1);

  hlayer<768, 512, true ><<<dim3(1024), dim3(512), 0, stream>>>(x,  zT1, st1, nullptr, h1, lam1);
  hlayer<512, 256, false><<<dim3(1024), dim3(512), 0, stream>>>(h1, zT2, st2, lam1,    h2, lam2);
  hlayer<256, 128, false><<<dim3(1024), dim3(512), 0, stream>>>(h2, zT3, st3, lam2,    h3, lam3);
  hlayer_last<<<dim3(1024), dim3(256), 0, stream>>>(h3, z4, st4, lam3, (float*)d_out);
}